// Round 12
// baseline (3840.448 us; speedup 1.0000x reference)
//
#include <hip/hip_runtime.h>

typedef unsigned short u16;
typedef unsigned int u32;

#define TB 64

// ---- graph constants (verbatim from reference) ----
__device__ static constexpr int PRED[6][2] = {{0,3},{1,5},{0,4},{2,7},{1,6},{2,8}};
__device__ static constexpr int EDG [6][2] = {{0,1},{0,2},{1,0},{1,2},{2,0},{2,1}};
__device__ static constexpr int INCM[3][2] = {{2,4},{0,5},{1,3}};

struct WPtrs { const float* p[32]; };

// ws layout (floats): ef [96][B] @0 ; h [384][B] @96B ; qk [12][B] @480B ; total 492*B

// =====================================================================
// Pass A: per (block.x=samples, block.y=object): 2 edge MLPs + edge attn -> ef
// LDS: rows 0..8 dg, 9..17 obj[:,:3], 18..33 hidden stage (34 rows = 8.7 KB)
// =====================================================================
extern "C" __global__ void __launch_bounds__(TB, 3)
pass_ef(const float* __restrict__ obs, const float* __restrict__ ag,
        const float* __restrict__ g, WPtrs wp, float* __restrict__ ws, int B)
{
  __shared__ float L[34*TB];
  const int tid = threadIdx.x;
  const int s = blockIdx.x*TB + tid;
  if (s >= B) return;
  const int o = blockIdx.y;
  #define LDR(r) L[(r)*TB + tid]

  #pragma unroll
  for(int k=0;k<9;k++) LDR(k) = g[s*9+k] - ag[s*9+k];
  #pragma unroll
  for(int oo=0;oo<3;oo++)
    #pragma unroll
    for(int i=0;i<3;i++) LDR(9+oo*3+i) = obs[s*55+10+15*oo+i];

  const float* W1=wp.p[0]; const float* B1=wp.p[1];
  const float* W2=wp.p[2]; const float* B2=wp.p[3];
  float* ef = ws;

  float v0[32], v1[32];
  float q0,k0,q1,k1;

  #pragma unroll
  for(int slot=0;slot<2;slot++){
    const int e = INCM[o][slot];
    // ---- mp MLP: 8 -> 256 relu -> 32 ----
    float o32[32];
    #pragma unroll
    for(int m=0;m<32;m++) o32[m]=B2[m];
    for(int c=0;c<4;c++){
      float hh[64];
      #pragma unroll
      for(int n=0;n<64;n++) hh[n]=B1[c*64+n];
      #pragma unroll
      for(int k=0;k<8;k++){
        const int row = (k<2) ? PRED[e][k] : (k<5) ? (9+3*EDG[e][0]+(k-2)) : (9+3*EDG[e][1]+(k-5));
        float xv = LDR(row);
        const float* w = W1 + k*256 + c*64;
        #pragma unroll
        for(int n=0;n<64;n++) hh[n]=fmaf(xv,w[n],hh[n]);
      }
      // layer-2 via 16-row wave-private staging
      #pragma unroll
      for(int g4=0;g4<4;g4++){
        #pragma unroll
        for(int t=0;t<16;t++) LDR(18+t)=fmaxf(hh[g4*16+t],0.f);
        for(int t=0;t<16;t++){
          float hv=LDR(18+t);
          const float* w = W2 + (c*64+g4*16+t)*32;
          #pragma unroll
          for(int m=0;m<32;m++) o32[m]=fmaf(hv,w[m],o32[m]);
        }
      }
    }
    // ---- per-token q,k,v ----
    float qt=wp.p[5][0], kt=wp.p[7][0];
    #pragma unroll
    for(int k=0;k<32;k++){ qt=fmaf(o32[k],wp.p[4][k],qt); kt=fmaf(o32[k],wp.p[6][k],kt); }
    float vt[32];
    #pragma unroll
    for(int n=0;n<32;n++) vt[n]=wp.p[9][n];
    #pragma unroll
    for(int k=0;k<32;k++){
      const float* w = wp.p[8] + k*32;
      #pragma unroll
      for(int n=0;n<32;n++) vt[n]=fmaf(o32[k],w[n],vt[n]);
    }
    if(slot==0){ q0=qt; k0=kt;
      #pragma unroll
      for(int n=0;n<32;n++) v0[n]=vt[n];
    } else { q1=qt; k1=kt;
      #pragma unroll
      for(int n=0;n<32;n++) v1[n]=vt[n];
    }
  }
  // 2x2 softmax over keys, summed over queries (exact column-sum form)
  float s00=q0*k0, s01=q0*k1, s10=q1*k0, s11=q1*k1;
  float m0=fmaxf(s00,s01), m1=fmaxf(s10,s11);
  float e00=expf(s00-m0), e01=expf(s01-m0), e10=expf(s10-m1), e11=expf(s11-m1);
  float d0=e00+e01, d1=e10+e11;
  float c0=e00/d0+e10/d1, c1=e01/d0+e11/d1;
  #pragma unroll
  for(int n=0;n<32;n++) ef[(o*32+n)*B + s] = fmaf(c0,v0[n], c1*v1[n]);
  #undef LDR
}

// =====================================================================
// Pass B1: per (block.x=samples, block.y=j): phi for BOTH sets -> h + qk
// LDS: rows 0..28 xin(base), 29..44 hidden stage (45 rows = 11.5 KB)
// ef part of xin streamed coalesced from ws (L1-cached across reps)
// =====================================================================
extern "C" __global__ void __launch_bounds__(TB, 3)
pass_phi(const float* __restrict__ obs, const float* __restrict__ act,
         WPtrs wp, float* __restrict__ ws, int B)
{
  __shared__ float L[45*TB];
  const int tid = threadIdx.x;
  const int s = blockIdx.x*TB + tid;
  if (s >= B) return;
  const int j = blockIdx.y;
  #define LDR(r) L[(r)*TB + tid]

  const float* ef = ws;
  float* h  = ws + 96*B;
  float* qk = ws + 480*B;

  #pragma unroll
  for(int k=0;k<4;k++)  LDR(k)    = act[s*4+k];
  #pragma unroll
  for(int k=0;k<10;k++) LDR(4+k)  = obs[s*55+k];
  #pragma unroll
  for(int k=0;k<15;k++) LDR(14+k) = obs[s*55+10+15*j+k];

  for(int set=0; set<2; set++){
    const int combo = set*3 + j;
    const float* pw1 = wp.p[set?14:10]; const float* pb1 = wp.p[set?15:11];
    const float* pw2 = wp.p[set?16:12]; const float* pb2 = wp.p[set?17:13];

    float o64[64];
    #pragma unroll
    for(int n=0;n<64;n++) o64[n]=pb2[n];

    for(int c=0;c<4;c++){
      float hh[64];
      #pragma unroll
      for(int n=0;n<64;n++) hh[n]=pb1[c*64+n];
      // layer-1: k<29 from LDS
      for(int k=0;k<29;k++){
        float xv = LDR(k);
        const float* w = pw1 + k*256 + c*64;
        #pragma unroll
        for(int n=0;n<64;n++) hh[n]=fmaf(xv,w[n],hh[n]);
      }
      // layer-1: k=29..60 from ef (coalesced global)
      for(int k=0;k<32;k++){
        float xv = ef[(j*32+k)*B + s];
        const float* w = pw1 + (29+k)*256 + c*64;
        #pragma unroll
        for(int n=0;n<64;n++) hh[n]=fmaf(xv,w[n],hh[n]);
      }
      // layer-2 via 16-row staging
      #pragma unroll
      for(int g4=0;g4<4;g4++){
        #pragma unroll
        for(int t=0;t<16;t++) LDR(29+t)=fmaxf(hh[g4*16+t],0.f);
        for(int t=0;t<16;t++){
          float hv=LDR(29+t);
          const float* w = pw2 + (c*64+g4*16+t)*64;
          #pragma unroll
          for(int n=0;n<64;n++) o64[n]=fmaf(hv,w[n],o64[n]);
        }
      }
    }
    // relu_out, h write, na q/k scalars
    float qj=wp.p[19][0], kj=wp.p[21][0];
    #pragma unroll
    for(int n=0;n<64;n++){
      float hv = fmaxf(o64[n],0.f);
      h[(combo*64+n)*B + s] = hv;
      qj = fmaf(hv, wp.p[18][n], qj);
      kj = fmaf(hv, wp.p[20][n], kj);
    }
    qk[(combo*2+0)*B + s] = qj;
    qk[(combo*2+1)*B + s] = kj;
  }
  #undef LDR
}

// =====================================================================
// Pass B2: per (block.x=samples, block.y=set): na attn (exact hoist) + rho
// LDS: rows 0..15 stage, 16..79 s64 (80 rows = 20.5 KB)
// =====================================================================
extern "C" __global__ void __launch_bounds__(TB, 3)
pass_rho(WPtrs wp, const float* __restrict__ ws, float* __restrict__ out, int B)
{
  __shared__ float L[80*TB];
  const int tid = threadIdx.x;
  const int s = blockIdx.x*TB + tid;
  if (s >= B) return;
  const int set = blockIdx.y;
  #define LDR(r) L[(r)*TB + tid]

  const float* h  = ws + 96*B;
  const float* qk = ws + 480*B;

  float qn[3], kn[3];
  #pragma unroll
  for(int t=0;t<3;t++){
    qn[t] = qk[((set*3+t)*2+0)*B + s];
    kn[t] = qk[((set*3+t)*2+1)*B + s];
  }
  float cw0=0.f, cw1=0.f, cw2=0.f;
  #pragma unroll
  for(int i=0;i<3;i++){
    float t0=qn[i]*kn[0], t1=qn[i]*kn[1], t2=qn[i]*kn[2];
    float mm=fmaxf(fmaxf(t0,t1),t2);
    float e0=expf(t0-mm), e1=expf(t1-mm), e2=expf(t2-mm);
    float dd=e0+e1+e2;
    cw0 += e0/dd; cw1 += e1/dd; cw2 += e2/dd;
  }

  // t64 in registers (coalesced h reads)
  float t64[64];
  #pragma unroll
  for(int n=0;n<64;n++){
    t64[n] = cw0*h[((set*3+0)*64+n)*B+s]
           + cw1*h[((set*3+1)*64+n)*B+s]
           + cw2*h[((set*3+2)*64+n)*B+s];
  }
  // s64 = t64 @ naWv + 3*nabv, via 16-row staging
  float s64[64];
  #pragma unroll
  for(int n=0;n<64;n++) s64[n] = 3.f*wp.p[23][n];
  #pragma unroll
  for(int g4=0;g4<4;g4++){
    #pragma unroll
    for(int t=0;t<16;t++) LDR(t)=t64[g4*16+t];
    for(int t=0;t<16;t++){
      float tv=LDR(t);
      const float* w = wp.p[22] + (g4*16+t)*64;
      #pragma unroll
      for(int n=0;n<64;n++) s64[n]=fmaf(tv,w[n],s64[n]);
    }
  }
  #pragma unroll
  for(int n=0;n<64;n++) LDR(16+n)=s64[n];

  // rho: 64 -> 256 relu -> 1
  const float* rw1=wp.p[set?28:24]; const float* rb1=wp.p[set?29:25];
  const float* rw2=wp.p[set?30:26];
  float qacc = wp.p[set?31:27][0];
  for(int c=0;c<4;c++){
    float hh[64];
    #pragma unroll
    for(int n=0;n<64;n++) hh[n]=rb1[c*64+n];
    for(int k=0;k<64;k++){
      float sv=LDR(16+k);
      const float* w = rw1 + k*256 + c*64;
      #pragma unroll
      for(int n=0;n<64;n++) hh[n]=fmaf(sv,w[n],hh[n]);
    }
    #pragma unroll
    for(int n=0;n<64;n++) qacc=fmaf(fmaxf(hh[n],0.f),rw2[c*64+n],qacc);
  }
  out[set*B + s] = qacc;
  #undef LDR
}

// =====================================================================
// Fallback: round-10 monolithic kernel (proven) if ws too small
// =====================================================================
#define R_MPH 68
#define R_EF  260
#define R_T   356
#define NROW  420

extern "C" __global__ void __launch_bounds__(TB, 1)
critic_mech(const float* __restrict__ obs, const float* __restrict__ act,
            const float* __restrict__ ag, const float* __restrict__ g,
            WPtrs wp, float* __restrict__ out, int B)
{
  extern __shared__ float L[];
  const int tid = threadIdx.x;
  const int s = blockIdx.x*TB + tid;
  if (s >= B) return;
  #define LDR(r) L[(r)*TB + tid]
  for(int k=0;k<4;k++)  LDR(k)      = act[s*4+k];
  for(int k=0;k<55;k++) LDR(4+k)    = obs[s*55+k];
  for(int k=0;k<9;k++)  LDR(59+k)   = g[s*9+k] - ag[s*9+k];
  {
    const float* W1=wp.p[0]; const float* B1=wp.p[1];
    const float* W2=wp.p[2]; const float* B2=wp.p[3];
    for(int e=0;e<6;e++){
      float xin[8];
      #pragma unroll
      for(int i=0;i<2;i++) xin[i]   = LDR(59 + PRED[e][i]);
      #pragma unroll
      for(int i=0;i<3;i++) xin[2+i] = LDR(4 + 10 + 15*EDG[e][0] + i);
      #pragma unroll
      for(int i=0;i<3;i++) xin[5+i] = LDR(4 + 10 + 15*EDG[e][1] + i);
      float o32[32];
      #pragma unroll
      for(int m=0;m<32;m++) o32[m]=B2[m];
      for(int c=0;c<4;c++){
        float hh[64];
        #pragma unroll
        for(int n=0;n<64;n++) hh[n]=B1[c*64+n];
        #pragma unroll
        for(int k=0;k<8;k++){
          const float* w = W1 + k*256 + c*64;
          #pragma unroll
          for(int n=0;n<64;n++) hh[n]=fmaf(xin[k],w[n],hh[n]);
        }
        #pragma unroll
        for(int n=0;n<64;n++) LDR(R_T+n)=fmaxf(hh[n],0.f);
        for(int n=0;n<64;n++){
          float hv=LDR(R_T+n);
          const float* w = W2 + (c*64+n)*32;
          #pragma unroll
          for(int m=0;m<32;m++) o32[m]=fmaf(hv,w[m],o32[m]);
        }
      }
      #pragma unroll
      for(int m=0;m<32;m++) LDR(R_MPH+e*32+m)=o32[m];
    }
  }
  for(int o=0;o<3;o++){
    float x0[32], x1[32];
    #pragma unroll
    for(int k=0;k<32;k++){
      x0[k]=LDR(R_MPH+INCM[o][0]*32+k);
      x1[k]=LDR(R_MPH+INCM[o][1]*32+k);
    }
    float q0=wp.p[5][0], q1=wp.p[5][0], k0=wp.p[7][0], k1=wp.p[7][0];
    #pragma unroll
    for(int k=0;k<32;k++){
      q0=fmaf(x0[k],wp.p[4][k],q0); q1=fmaf(x1[k],wp.p[4][k],q1);
      k0=fmaf(x0[k],wp.p[6][k],k0); k1=fmaf(x1[k],wp.p[6][k],k1);
    }
    float v0[32], v1[32];
    #pragma unroll
    for(int n=0;n<32;n++){ v0[n]=wp.p[9][n]; v1[n]=wp.p[9][n]; }
    #pragma unroll
    for(int k=0;k<32;k++){
      const float* w = wp.p[8] + k*32;
      #pragma unroll
      for(int n=0;n<32;n++){ v0[n]=fmaf(x0[k],w[n],v0[n]); v1[n]=fmaf(x1[k],w[n],v1[n]); }
    }
    float s00=q0*k0, s01=q0*k1, s10=q1*k0, s11=q1*k1;
    float m0=fmaxf(s00,s01), m1=fmaxf(s10,s11);
    float e00=expf(s00-m0), e01=expf(s01-m0), e10=expf(s10-m1), e11=expf(s11-m1);
    float d0=e00+e01, d1=e10+e11;
    float a00=e00/d0, a01=e01/d0, a10=e10/d1, a11=e11/d1;
    #pragma unroll
    for(int n=0;n<32;n++)
      LDR(R_EF+o*32+n) = (a00*v0[n]+a01*v1[n]) + (a10*v0[n]+a11*v1[n]);
  }
  for(int set=0; set<2; set++){
    const float* pw1=wp.p[set?14:10]; const float* pb1=wp.p[set?15:11];
    const float* pw2=wp.p[set?16:12]; const float* pb2=wp.p[set?17:13];
    for(int j=0;j<3;j++){
      float o64[64];
      #pragma unroll
      for(int n=0;n<64;n++) o64[n]=pb2[n];
      for(int c=0;c<4;c++){
        float hh[64];
        #pragma unroll
        for(int n=0;n<64;n++) hh[n]=pb1[c*64+n];
        for(int k=0;k<61;k++){
          int row = (k<14) ? k : (k<29) ? (4+10+15*j+(k-14)) : (R_EF+32*j+(k-29));
          float xv = LDR(row);
          const float* w = pw1 + k*256 + c*64;
          #pragma unroll
          for(int n=0;n<64;n++) hh[n]=fmaf(xv,w[n],hh[n]);
        }
        #pragma unroll
        for(int n=0;n<64;n++) LDR(R_T+n)=fmaxf(hh[n],0.f);
        for(int n=0;n<64;n++){
          float hv=LDR(R_T+n);
          const float* w = pw2 + (c*64+n)*64;
          #pragma unroll
          for(int m=0;m<64;m++) o64[m]=fmaf(hv,w[m],o64[m]);
        }
      }
      #pragma unroll
      for(int n=0;n<64;n++) LDR(R_MPH+j*64+n)=fmaxf(o64[n],0.f);
    }
    float qn[3], kn[3];
    #pragma unroll
    for(int j=0;j<3;j++){
      float qq=wp.p[19][0], kk=wp.p[21][0];
      for(int n=0;n<64;n++){
        float hv=LDR(R_MPH+j*64+n);
        qq=fmaf(hv,wp.p[18][n],qq);
        kk=fmaf(hv,wp.p[20][n],kk);
      }
      qn[j]=qq; kn[j]=kk;
    }
    float cw0=0.f,cw1=0.f,cw2=0.f;
    #pragma unroll
    for(int i=0;i<3;i++){
      float t0=qn[i]*kn[0], t1=qn[i]*kn[1], t2=qn[i]*kn[2];
      float mm=fmaxf(fmaxf(t0,t1),t2);
      float e0=expf(t0-mm), e1=expf(t1-mm), e2=expf(t2-mm);
      float dd=e0+e1+e2;
      cw0+=e0/dd; cw1+=e1/dd; cw2+=e2/dd;
    }
    #pragma unroll
    for(int n=0;n<64;n++)
      LDR(R_T+n) = cw0*LDR(R_MPH+0*64+n) + cw1*LDR(R_MPH+1*64+n) + cw2*LDR(R_MPH+2*64+n);
    float s64[64];
    #pragma unroll
    for(int n=0;n<64;n++) s64[n] = 3.f*wp.p[23][n];
    for(int k=0;k<64;k++){
      float xv = LDR(R_T+k);
      const float* w = wp.p[22] + k*64;
      #pragma unroll
      for(int n=0;n<64;n++) s64[n]=fmaf(xv,w[n],s64[n]);
    }
    #pragma unroll
    for(int n=0;n<64;n++) LDR(R_T+n)=s64[n];
    const float* rw1=wp.p[set?28:24]; const float* rb1=wp.p[set?29:25];
    const float* rw2=wp.p[set?30:26];
    float qacc = wp.p[set?31:27][0];
    for(int c=0;c<4;c++){
      float hh[64];
      #pragma unroll
      for(int n=0;n<64;n++) hh[n]=rb1[c*64+n];
      for(int k=0;k<64;k++){
        float sv=LDR(R_T+k);
        const float* w = rw1 + k*256 + c*64;
        #pragma unroll
        for(int n=0;n<64;n++) hh[n]=fmaf(sv,w[n],hh[n]);
      }
      #pragma unroll
      for(int n=0;n<64;n++) qacc=fmaf(fmaxf(hh[n],0.f),rw2[c*64+n],qacc);
    }
    out[set*B + s] = qacc;
  }
  #undef LDR
}

extern "C" __global__ void sentinel_fill(float* out, int n, float val){
  int i = blockIdx.x*blockDim.x + threadIdx.x;
  for(; i<n; i += gridDim.x*blockDim.x) out[i] = val;
}

extern "C" void kernel_launch(void* const* d_in, const int* in_sizes, int n_in,
                              void* d_out, int out_size, void* d_ws, size_t ws_size,
                              hipStream_t stream) {
  float* out = (float*)d_out;
  if (n_in != 36) { hipLaunchKernelGGL(sentinel_fill, dim3(256), dim3(256), 0, stream, out, out_size, 9000.0f); return; }
  const int B = in_sizes[0] / 55;
  if (out_size != 2*B) { hipLaunchKernelGGL(sentinel_fill, dim3(256), dim3(256), 0, stream, out, out_size, 7777.0f); return; }

  const float* obs = (const float*)d_in[0];
  const float* act = (const float*)d_in[1];
  const float* ag  = (const float*)d_in[2];
  const float* g   = (const float*)d_in[3];
  WPtrs wp;
  for(int i=0;i<32;i++) wp.p[i] = (const float*)d_in[4+i];

  const size_t ws_need = (size_t)492 * B * sizeof(float);
  const int nb = (B + TB - 1)/TB;

  if (ws_size >= ws_need) {
    float* ws = (float*)d_ws;
    hipLaunchKernelGGL(pass_ef,  dim3(nb, 3), dim3(TB), 0, stream, obs, ag, g, wp, ws, B);
    hipLaunchKernelGGL(pass_phi, dim3(nb, 3), dim3(TB), 0, stream, obs, act, wp, ws, B);
    hipLaunchKernelGGL(pass_rho, dim3(nb, 2), dim3(TB), 0, stream, wp, ws, out, B);
  } else {
    const size_t lds_bytes = (size_t)NROW * TB * sizeof(float);
    hipLaunchKernelGGL(critic_mech, dim3(nb), dim3(TB), lds_bytes, stream,
                       obs, act, ag, g, wp, out, B);
  }
}

// Round 13
// 2623.506 us; speedup vs baseline: 1.4639x; 1.4639x over previous
//
#include <hip/hip_runtime.h>

typedef unsigned short u16;
typedef unsigned int u32;

#define TB 64

// ---- graph constants (verbatim from reference) ----
__device__ static constexpr int PRED[6][2] = {{0,3},{1,5},{0,4},{2,7},{1,6},{2,8}};
__device__ static constexpr int EDG [6][2] = {{0,1},{0,2},{1,0},{1,2},{2,0},{2,1}};
__device__ static constexpr int INCM[3][2] = {{2,4},{0,5},{1,3}};

struct WPtrs { const float* p[32]; };

// ws layout (floats): ef [96][B] @0 ; h [384][B] @96B ; qk [12][B] @480B ; total 492*B

// =====================================================================
// Pass A: per (block.x=samples, block.y=object): 2 edge MLPs + edge attn -> ef
// LDS: rows 0..8 dg, 9..17 obj[:,:3], 18..33 hidden stage (34 rows = 8.7 KB)
// launch_bounds(64,2): 256-reg unified budget -> no scratch spills (r12 lesson)
// =====================================================================
extern "C" __global__ void __launch_bounds__(TB, 2)
pass_ef(const float* __restrict__ obs, const float* __restrict__ ag,
        const float* __restrict__ g, WPtrs wp, float* __restrict__ ws, int B)
{
  __shared__ float L[34*TB];
  const int tid = threadIdx.x;
  const int s = blockIdx.x*TB + tid;
  if (s >= B) return;
  const int o = blockIdx.y;
  #define LDR(r) L[(r)*TB + tid]

  #pragma unroll
  for(int k=0;k<9;k++) LDR(k) = g[s*9+k] - ag[s*9+k];
  #pragma unroll
  for(int oo=0;oo<3;oo++)
    #pragma unroll
    for(int i=0;i<3;i++) LDR(9+oo*3+i) = obs[s*55+10+15*oo+i];

  const float* W1=wp.p[0]; const float* B1=wp.p[1];
  const float* W2=wp.p[2]; const float* B2=wp.p[3];
  float* ef = ws;

  float v0[32], v1[32];
  float q0,k0,q1,k1;

  #pragma unroll
  for(int slot=0;slot<2;slot++){
    const int e = INCM[o][slot];
    // ---- mp MLP: 8 -> 256 relu -> 32 ----
    float o32[32];
    #pragma unroll
    for(int m=0;m<32;m++) o32[m]=B2[m];
    for(int c=0;c<4;c++){
      float hh[64];
      #pragma unroll
      for(int n=0;n<64;n++) hh[n]=B1[c*64+n];
      #pragma unroll
      for(int k=0;k<8;k++){
        const int row = (k<2) ? PRED[e][k] : (k<5) ? (9+3*EDG[e][0]+(k-2)) : (9+3*EDG[e][1]+(k-5));
        float xv = LDR(row);
        const float* w = W1 + k*256 + c*64;
        #pragma unroll
        for(int n=0;n<64;n++) hh[n]=fmaf(xv,w[n],hh[n]);
      }
      // layer-2 via 16-row wave-private staging
      #pragma unroll
      for(int g4=0;g4<4;g4++){
        #pragma unroll
        for(int t=0;t<16;t++) LDR(18+t)=fmaxf(hh[g4*16+t],0.f);
        for(int t=0;t<16;t++){
          float hv=LDR(18+t);
          const float* w = W2 + (c*64+g4*16+t)*32;
          #pragma unroll
          for(int m=0;m<32;m++) o32[m]=fmaf(hv,w[m],o32[m]);
        }
      }
    }
    // ---- per-token q,k,v ----
    float qt=wp.p[5][0], kt=wp.p[7][0];
    #pragma unroll
    for(int k=0;k<32;k++){ qt=fmaf(o32[k],wp.p[4][k],qt); kt=fmaf(o32[k],wp.p[6][k],kt); }
    float vt[32];
    #pragma unroll
    for(int n=0;n<32;n++) vt[n]=wp.p[9][n];
    #pragma unroll
    for(int k=0;k<32;k++){
      const float* w = wp.p[8] + k*32;
      #pragma unroll
      for(int n=0;n<32;n++) vt[n]=fmaf(o32[k],w[n],vt[n]);
    }
    if(slot==0){ q0=qt; k0=kt;
      #pragma unroll
      for(int n=0;n<32;n++) v0[n]=vt[n];
    } else { q1=qt; k1=kt;
      #pragma unroll
      for(int n=0;n<32;n++) v1[n]=vt[n];
    }
  }
  // 2x2 softmax over keys, summed over queries (exact column-sum form)
  float s00=q0*k0, s01=q0*k1, s10=q1*k0, s11=q1*k1;
  float m0=fmaxf(s00,s01), m1=fmaxf(s10,s11);
  float e00=expf(s00-m0), e01=expf(s01-m0), e10=expf(s10-m1), e11=expf(s11-m1);
  float d0=e00+e01, d1=e10+e11;
  float c0=e00/d0+e10/d1, c1=e01/d0+e11/d1;
  #pragma unroll
  for(int n=0;n<32;n++) ef[(o*32+n)*B + s] = fmaf(c0,v0[n], c1*v1[n]);
  #undef LDR
}

// =====================================================================
// Pass B1: per (block.x=samples, block.y=j): phi for BOTH sets -> h + qk
// LDS: rows 0..28 xin(base), 29..44 hidden stage (45 rows = 11.5 KB)
// launch_bounds(64,2): r12's (64,3) caused 3 GB scratch spill traffic
// =====================================================================
extern "C" __global__ void __launch_bounds__(TB, 2)
pass_phi(const float* __restrict__ obs, const float* __restrict__ act,
         WPtrs wp, float* __restrict__ ws, int B)
{
  __shared__ float L[45*TB];
  const int tid = threadIdx.x;
  const int s = blockIdx.x*TB + tid;
  if (s >= B) return;
  const int j = blockIdx.y;
  #define LDR(r) L[(r)*TB + tid]

  const float* ef = ws;
  float* h  = ws + 96*B;
  float* qk = ws + 480*B;

  #pragma unroll
  for(int k=0;k<4;k++)  LDR(k)    = act[s*4+k];
  #pragma unroll
  for(int k=0;k<10;k++) LDR(4+k)  = obs[s*55+k];
  #pragma unroll
  for(int k=0;k<15;k++) LDR(14+k) = obs[s*55+10+15*j+k];

  for(int set=0; set<2; set++){
    const int combo = set*3 + j;
    const float* pw1 = wp.p[set?14:10]; const float* pb1 = wp.p[set?15:11];
    const float* pw2 = wp.p[set?16:12]; const float* pb2 = wp.p[set?17:13];

    float o64[64];
    #pragma unroll
    for(int n=0;n<64;n++) o64[n]=pb2[n];

    for(int c=0;c<4;c++){
      float hh[64];
      #pragma unroll
      for(int n=0;n<64;n++) hh[n]=pb1[c*64+n];
      // layer-1: k<29 from LDS
      for(int k=0;k<29;k++){
        float xv = LDR(k);
        const float* w = pw1 + k*256 + c*64;
        #pragma unroll
        for(int n=0;n<64;n++) hh[n]=fmaf(xv,w[n],hh[n]);
      }
      // layer-1: k=29..60 from ef (coalesced global, L1/L2-cached across reps)
      for(int k=0;k<32;k++){
        float xv = ef[(j*32+k)*B + s];
        const float* w = pw1 + (29+k)*256 + c*64;
        #pragma unroll
        for(int n=0;n<64;n++) hh[n]=fmaf(xv,w[n],hh[n]);
      }
      // layer-2 via 16-row staging
      #pragma unroll
      for(int g4=0;g4<4;g4++){
        #pragma unroll
        for(int t=0;t<16;t++) LDR(29+t)=fmaxf(hh[g4*16+t],0.f);
        for(int t=0;t<16;t++){
          float hv=LDR(29+t);
          const float* w = pw2 + (c*64+g4*16+t)*64;
          #pragma unroll
          for(int n=0;n<64;n++) o64[n]=fmaf(hv,w[n],o64[n]);
        }
      }
    }
    // relu_out, h write, na q/k scalars
    float qj=wp.p[19][0], kj=wp.p[21][0];
    #pragma unroll
    for(int n=0;n<64;n++){
      float hv = fmaxf(o64[n],0.f);
      h[(combo*64+n)*B + s] = hv;
      qj = fmaf(hv, wp.p[18][n], qj);
      kj = fmaf(hv, wp.p[20][n], kj);
    }
    qk[(combo*2+0)*B + s] = qj;
    qk[(combo*2+1)*B + s] = kj;
  }
  #undef LDR
}

// =====================================================================
// Pass B2: per (block.x=samples, block.y=set): na attn (exact hoist) + rho
// LDS: rows 0..15 stage, 16..79 s64 (80 rows = 20.5 KB)
// =====================================================================
extern "C" __global__ void __launch_bounds__(TB, 2)
pass_rho(WPtrs wp, const float* __restrict__ ws, float* __restrict__ out, int B)
{
  __shared__ float L[80*TB];
  const int tid = threadIdx.x;
  const int s = blockIdx.x*TB + tid;
  if (s >= B) return;
  const int set = blockIdx.y;
  #define LDR(r) L[(r)*TB + tid]

  const float* h  = ws + 96*B;
  const float* qk = ws + 480*B;

  float qn[3], kn[3];
  #pragma unroll
  for(int t=0;t<3;t++){
    qn[t] = qk[((set*3+t)*2+0)*B + s];
    kn[t] = qk[((set*3+t)*2+1)*B + s];
  }
  float cw0=0.f, cw1=0.f, cw2=0.f;
  #pragma unroll
  for(int i=0;i<3;i++){
    float t0=qn[i]*kn[0], t1=qn[i]*kn[1], t2=qn[i]*kn[2];
    float mm=fmaxf(fmaxf(t0,t1),t2);
    float e0=expf(t0-mm), e1=expf(t1-mm), e2=expf(t2-mm);
    float dd=e0+e1+e2;
    cw0 += e0/dd; cw1 += e1/dd; cw2 += e2/dd;
  }

  // t64 in registers (coalesced h reads)
  float t64[64];
  #pragma unroll
  for(int n=0;n<64;n++){
    t64[n] = cw0*h[((set*3+0)*64+n)*B+s]
           + cw1*h[((set*3+1)*64+n)*B+s]
           + cw2*h[((set*3+2)*64+n)*B+s];
  }
  // s64 = t64 @ naWv + 3*nabv, via 16-row staging
  float s64[64];
  #pragma unroll
  for(int n=0;n<64;n++) s64[n] = 3.f*wp.p[23][n];
  #pragma unroll
  for(int g4=0;g4<4;g4++){
    #pragma unroll
    for(int t=0;t<16;t++) LDR(t)=t64[g4*16+t];
    for(int t=0;t<16;t++){
      float tv=LDR(t);
      const float* w = wp.p[22] + (g4*16+t)*64;
      #pragma unroll
      for(int n=0;n<64;n++) s64[n]=fmaf(tv,w[n],s64[n]);
    }
  }
  #pragma unroll
  for(int n=0;n<64;n++) LDR(16+n)=s64[n];

  // rho: 64 -> 256 relu -> 1
  const float* rw1=wp.p[set?28:24]; const float* rb1=wp.p[set?29:25];
  const float* rw2=wp.p[set?30:26];
  float qacc = wp.p[set?31:27][0];
  for(int c=0;c<4;c++){
    float hh[64];
    #pragma unroll
    for(int n=0;n<64;n++) hh[n]=rb1[c*64+n];
    for(int k=0;k<64;k++){
      float sv=LDR(16+k);
      const float* w = rw1 + k*256 + c*64;
      #pragma unroll
      for(int n=0;n<64;n++) hh[n]=fmaf(sv,w[n],hh[n]);
    }
    #pragma unroll
    for(int n=0;n<64;n++) qacc=fmaf(fmaxf(hh[n],0.f),rw2[c*64+n],qacc);
  }
  out[set*B + s] = qacc;
  #undef LDR
}

// =====================================================================
// Fallback: round-10 monolithic kernel (proven) if ws too small
// =====================================================================
#define R_MPH 68
#define R_EF  260
#define R_T   356
#define NROW  420

extern "C" __global__ void __launch_bounds__(TB, 1)
critic_mech(const float* __restrict__ obs, const float* __restrict__ act,
            const float* __restrict__ ag, const float* __restrict__ g,
            WPtrs wp, float* __restrict__ out, int B)
{
  extern __shared__ float L[];
  const int tid = threadIdx.x;
  const int s = blockIdx.x*TB + tid;
  if (s >= B) return;
  #define LDR(r) L[(r)*TB + tid]
  for(int k=0;k<4;k++)  LDR(k)      = act[s*4+k];
  for(int k=0;k<55;k++) LDR(4+k)    = obs[s*55+k];
  for(int k=0;k<9;k++)  LDR(59+k)   = g[s*9+k] - ag[s*9+k];
  {
    const float* W1=wp.p[0]; const float* B1=wp.p[1];
    const float* W2=wp.p[2]; const float* B2=wp.p[3];
    for(int e=0;e<6;e++){
      float xin[8];
      #pragma unroll
      for(int i=0;i<2;i++) xin[i]   = LDR(59 + PRED[e][i]);
      #pragma unroll
      for(int i=0;i<3;i++) xin[2+i] = LDR(4 + 10 + 15*EDG[e][0] + i);
      #pragma unroll
      for(int i=0;i<3;i++) xin[5+i] = LDR(4 + 10 + 15*EDG[e][1] + i);
      float o32[32];
      #pragma unroll
      for(int m=0;m<32;m++) o32[m]=B2[m];
      for(int c=0;c<4;c++){
        float hh[64];
        #pragma unroll
        for(int n=0;n<64;n++) hh[n]=B1[c*64+n];
        #pragma unroll
        for(int k=0;k<8;k++){
          const float* w = W1 + k*256 + c*64;
          #pragma unroll
          for(int n=0;n<64;n++) hh[n]=fmaf(xin[k],w[n],hh[n]);
        }
        #pragma unroll
        for(int n=0;n<64;n++) LDR(R_T+n)=fmaxf(hh[n],0.f);
        for(int n=0;n<64;n++){
          float hv=LDR(R_T+n);
          const float* w = W2 + (c*64+n)*32;
          #pragma unroll
          for(int m=0;m<32;m++) o32[m]=fmaf(hv,w[m],o32[m]);
        }
      }
      #pragma unroll
      for(int m=0;m<32;m++) LDR(R_MPH+e*32+m)=o32[m];
    }
  }
  for(int o=0;o<3;o++){
    float x0[32], x1[32];
    #pragma unroll
    for(int k=0;k<32;k++){
      x0[k]=LDR(R_MPH+INCM[o][0]*32+k);
      x1[k]=LDR(R_MPH+INCM[o][1]*32+k);
    }
    float q0=wp.p[5][0], q1=wp.p[5][0], k0=wp.p[7][0], k1=wp.p[7][0];
    #pragma unroll
    for(int k=0;k<32;k++){
      q0=fmaf(x0[k],wp.p[4][k],q0); q1=fmaf(x1[k],wp.p[4][k],q1);
      k0=fmaf(x0[k],wp.p[6][k],k0); k1=fmaf(x1[k],wp.p[6][k],k1);
    }
    float v0[32], v1[32];
    #pragma unroll
    for(int n=0;n<32;n++){ v0[n]=wp.p[9][n]; v1[n]=wp.p[9][n]; }
    #pragma unroll
    for(int k=0;k<32;k++){
      const float* w = wp.p[8] + k*32;
      #pragma unroll
      for(int n=0;n<32;n++){ v0[n]=fmaf(x0[k],w[n],v0[n]); v1[n]=fmaf(x1[k],w[n],v1[n]); }
    }
    float s00=q0*k0, s01=q0*k1, s10=q1*k0, s11=q1*k1;
    float m0=fmaxf(s00,s01), m1=fmaxf(s10,s11);
    float e00=expf(s00-m0), e01=expf(s01-m0), e10=expf(s10-m1), e11=expf(s11-m1);
    float d0=e00+e01, d1=e10+e11;
    float a00=e00/d0, a01=e01/d0, a10=e10/d1, a11=e11/d1;
    #pragma unroll
    for(int n=0;n<32;n++)
      LDR(R_EF+o*32+n) = (a00*v0[n]+a01*v1[n]) + (a10*v0[n]+a11*v1[n]);
  }
  for(int set=0; set<2; set++){
    const float* pw1=wp.p[set?14:10]; const float* pb1=wp.p[set?15:11];
    const float* pw2=wp.p[set?16:12]; const float* pb2=wp.p[set?17:13];
    for(int j=0;j<3;j++){
      float o64[64];
      #pragma unroll
      for(int n=0;n<64;n++) o64[n]=pb2[n];
      for(int c=0;c<4;c++){
        float hh[64];
        #pragma unroll
        for(int n=0;n<64;n++) hh[n]=pb1[c*64+n];
        for(int k=0;k<61;k++){
          int row = (k<14) ? k : (k<29) ? (4+10+15*j+(k-14)) : (R_EF+32*j+(k-29));
          float xv = LDR(row);
          const float* w = pw1 + k*256 + c*64;
          #pragma unroll
          for(int n=0;n<64;n++) hh[n]=fmaf(xv,w[n],hh[n]);
        }
        #pragma unroll
        for(int n=0;n<64;n++) LDR(R_T+n)=fmaxf(hh[n],0.f);
        for(int n=0;n<64;n++){
          float hv=LDR(R_T+n);
          const float* w = pw2 + (c*64+n)*64;
          #pragma unroll
          for(int m=0;m<64;m++) o64[m]=fmaf(hv,w[m],o64[m]);
        }
      }
      #pragma unroll
      for(int n=0;n<64;n++) LDR(R_MPH+j*64+n)=fmaxf(o64[n],0.f);
    }
    float qn[3], kn[3];
    #pragma unroll
    for(int j=0;j<3;j++){
      float qq=wp.p[19][0], kk=wp.p[21][0];
      for(int n=0;n<64;n++){
        float hv=LDR(R_MPH+j*64+n);
        qq=fmaf(hv,wp.p[18][n],qq);
        kk=fmaf(hv,wp.p[20][n],kk);
      }
      qn[j]=qq; kn[j]=kk;
    }
    float cw0=0.f,cw1=0.f,cw2=0.f;
    #pragma unroll
    for(int i=0;i<3;i++){
      float t0=qn[i]*kn[0], t1=qn[i]*kn[1], t2=qn[i]*kn[2];
      float mm=fmaxf(fmaxf(t0,t1),t2);
      float e0=expf(t0-mm), e1=expf(t1-mm), e2=expf(t2-mm);
      float dd=e0+e1+e2;
      cw0+=e0/dd; cw1+=e1/dd; cw2+=e2/dd;
    }
    #pragma unroll
    for(int n=0;n<64;n++)
      LDR(R_T+n) = cw0*LDR(R_MPH+0*64+n) + cw1*LDR(R_MPH+1*64+n) + cw2*LDR(R_MPH+2*64+n);
    float s64[64];
    #pragma unroll
    for(int n=0;n<64;n++) s64[n] = 3.f*wp.p[23][n];
    for(int k=0;k<64;k++){
      float xv = LDR(R_T+k);
      const float* w = wp.p[22] + k*64;
      #pragma unroll
      for(int n=0;n<64;n++) s64[n]=fmaf(xv,w[n],s64[n]);
    }
    #pragma unroll
    for(int n=0;n<64;n++) LDR(R_T+n)=s64[n];
    const float* rw1=wp.p[set?28:24]; const float* rb1=wp.p[set?29:25];
    const float* rw2=wp.p[set?30:26];
    float qacc = wp.p[set?31:27][0];
    for(int c=0;c<4;c++){
      float hh[64];
      #pragma unroll
      for(int n=0;n<64;n++) hh[n]=rb1[c*64+n];
      for(int k=0;k<64;k++){
        float sv=LDR(R_T+k);
        const float* w = rw1 + k*256 + c*64;
        #pragma unroll
        for(int n=0;n<64;n++) hh[n]=fmaf(sv,w[n],hh[n]);
      }
      #pragma unroll
      for(int n=0;n<64;n++) qacc=fmaf(fmaxf(hh[n],0.f),rw2[c*64+n],qacc);
    }
    out[set*B + s] = qacc;
  }
  #undef LDR
}

extern "C" __global__ void sentinel_fill(float* out, int n, float val){
  int i = blockIdx.x*blockDim.x + threadIdx.x;
  for(; i<n; i += gridDim.x*blockDim.x) out[i] = val;
}

extern "C" void kernel_launch(void* const* d_in, const int* in_sizes, int n_in,
                              void* d_out, int out_size, void* d_ws, size_t ws_size,
                              hipStream_t stream) {
  float* out = (float*)d_out;
  if (n_in != 36) { hipLaunchKernelGGL(sentinel_fill, dim3(256), dim3(256), 0, stream, out, out_size, 9000.0f); return; }
  const int B = in_sizes[0] / 55;
  if (out_size != 2*B) { hipLaunchKernelGGL(sentinel_fill, dim3(256), dim3(256), 0, stream, out, out_size, 7777.0f); return; }

  const float* obs = (const float*)d_in[0];
  const float* act = (const float*)d_in[1];
  const float* ag  = (const float*)d_in[2];
  const float* g   = (const float*)d_in[3];
  WPtrs wp;
  for(int i=0;i<32;i++) wp.p[i] = (const float*)d_in[4+i];

  const size_t ws_need = (size_t)492 * B * sizeof(float);
  const int nb = (B + TB - 1)/TB;

  if (ws_size >= ws_need) {
    float* ws = (float*)d_ws;
    hipLaunchKernelGGL(pass_ef,  dim3(nb, 3), dim3(TB), 0, stream, obs, ag, g, wp, ws, B);
    hipLaunchKernelGGL(pass_phi, dim3(nb, 3), dim3(TB), 0, stream, obs, act, wp, ws, B);
    hipLaunchKernelGGL(pass_rho, dim3(nb, 2), dim3(TB), 0, stream, wp, ws, out, B);
  } else {
    const size_t lds_bytes = (size_t)NROW * TB * sizeof(float);
    hipLaunchKernelGGL(critic_mech, dim3(nb), dim3(TB), lds_bytes, stream,
                       obs, act, ag, g, wp, out, B);
  }
}